// Round 5
// baseline (198.221 us; speedup 1.0000x reference)
//
#include <hip/hip_runtime.h>

// Problem constants (from reference)
#define Nn 1024
#define Hh 96
#define Ee 16384
#define IN_K 9       // IN_RAW-1
#define IN_STRIDE 10 // x is (N, 10), we use first 9 cols
#define NH (Nn * Hh)
#define XS 128       // padded row stride for x-like (N,96) buffers
#define SLOTS 64     // per-row neighbor capacity (Poisson(16); P(>64) ~ 0)

__device__ __forceinline__ float sigf(float v) {
    return __builtin_amdgcn_rcpf(1.0f + __expf(-v));
}
__device__ __forceinline__ float tanhfast(float v) {
    float e = __expf(2.0f * v);
    return (e - 1.0f) * __builtin_amdgcn_rcpf(e + 1.0f);
}
__device__ __forceinline__ float leakyf(float v) {
    return v >= 0.0f ? v : 0.01f * v;
}

// ---------------- K0: setup (transposes + Wf fold + init linear) -----------
// grid 96 x 1024 covers max range NH=98304. No edge work, no atomics.
__global__ __launch_bounds__(1024) void setup_kernel(
    const float* __restrict__ W_hh, const float* __restrict__ Wa1,
    const float* __restrict__ Wo1, const float* __restrict__ Wo2,
    const float* __restrict__ W_ggc, const float* __restrict__ W_ih,
    const float* __restrict__ x_in, const float* __restrict__ W_init,
    const float* __restrict__ b_init,
    float* __restrict__ Wt_hh, float* __restrict__ Wt_a1i,
    float* __restrict__ Wt_a1j, float* __restrict__ Wt_o1,
    float* __restrict__ Wt_o2, float* __restrict__ Wf,
    float* __restrict__ xA)
{
    int gt = blockIdx.x * 1024 + threadIdx.x;
    if (gt < 64512) {   // transposes: Wt_hh 27648 + 4x9216
        int idx = gt;
        if (idx < 27648) {
            int k = idx / 288, c = idx % 288;
            Wt_hh[idx] = W_hh[c * 96 + k];
        } else if ((idx -= 27648) < 9216) {
            int k = idx / 96, h2 = idx % 96;
            Wt_a1i[idx] = Wa1[h2 * 192 + k];
        } else if ((idx -= 9216) < 9216) {
            int k = idx / 96, h2 = idx % 96;
            Wt_a1j[idx] = Wa1[h2 * 192 + 96 + k];
        } else if ((idx -= 9216) < 9216) {
            int k = idx / 96, j = idx % 96;
            Wt_o1[idx] = Wo1[j * 96 + k];
        } else {
            idx -= 9216;
            int k = idx / 96, j = idx % 96;
            Wt_o2[idx] = Wo2[j * 96 + k];
        }
    }
    if (gt < 27648) {   // Wf[k][c] = sum_j W_ggc[k][j] * W_ih[c][j]
        int k = gt / 288, c = gt % 288;
        const float* g = W_ggc + k * 96;
        const float* w = W_ih + c * 96;
        float acc = 0.0f;
        for (int j = 0; j < 96; ++j) acc += g[j] * w[j];
        Wf[gt] = acc;
    }
    if (gt < NH) {      // init linear
        int n = gt / Hh, j = gt - n * Hh;
        const float* xr = x_in + n * IN_STRIDE;
        const float* wr = W_init + j * IN_K;
        float acc = b_init[j];
#pragma unroll
        for (int k = 0; k < IN_K; ++k) acc += xr[k] * wr[k];
        xA[n * XS + j] = leakyf(acc);
    }
}

// ---------------- K1/K3: gru, 4 rows/block, 768 threads --------------------
// Per-block LDS CSR: scan the constant tgt array (64 KB, L2-resident) and
// collect sources for this block's 4 rows into LDS lists. No global deg/
// bucket arrays, no host memset node, no global atomics.
// Weight-register-sharing: each weight load feeds 4 rows. Gate dots are
// full-K per thread. LDS ~27 KB.
struct GShm {
    int   cnt[4];               // per-row edge counts (true counts)
    int   lst[4][SLOTS];        // per-row source lists
    float Pm[4][Hh];            // per-row gather mean
    float Xr[4][Hh];            // per-row x
    float Xo[4][Hh];            // per-row GRU output
    float gd[6][4][Hh];         // full-K gate dots [gate][row][h]
    float redp[2][4][4][Hh];    // proj partials [w][q][row][h]
};

__global__ __launch_bounds__(768) void gru_kernel(
    const float* __restrict__ xin, const int* __restrict__ ei,
    const float* __restrict__ Wf, const float* __restrict__ Wt_hh,
    const float* __restrict__ b_ih, const float* __restrict__ b_hh,
    const float* __restrict__ Wt_a1i, const float* __restrict__ Wt_a1j,
    const float* __restrict__ ba1,
    float* __restrict__ xout, float* __restrict__ Ei, float* __restrict__ EjT)
{
    __shared__ GShm sh;
    int tid = threadIdx.x;
    int i0 = blockIdx.x * 4;

    // A0: build this block's neighbor lists from the edge array
    if (tid < 4) sh.cnt[tid] = 0;
    __syncthreads();
    for (int e = tid; e < Ee; e += 768) {
        int tgt = ei[Ee + e];               // coalesced, L2-hit
        unsigned r = (unsigned)(tgt - i0);
        if (r < 4u) {
            int slot = atomicAdd(&sh.cnt[r], 1);
            if (slot < SLOTS) sh.lst[r][slot] = ei[e];
        }
    }
    __syncthreads();

    // A1: gather + mean, 384 threads (r, h), full row per thread
    if (tid < 384) {
        int h = tid % Hh, rr = tid / Hh;
        int d = sh.cnt[rr];
        int dc = d < SLOTS ? d : SLOTS;
        float acc = 0.0f;
        for (int s = 0; s < dc; ++s)
            acc += xin[sh.lst[rr][s] * XS + h];   // lst[rr][s]: LDS broadcast
        float inv = __builtin_amdgcn_rcpf(fmaxf((float)d, 1.0f));
        sh.Pm[rr][h] = acc * inv;
        sh.Xr[rr][h] = xin[(i0 + rr) * XS + h];
    }
    __syncthreads();

    // B: 6 gate dots, 576 threads (gate, h), full K=96, 4 rows in registers
    if (tid < 576) {
        int h = tid % Hh;
        int g = tid / Hh;              // 0..2: i-path (Wf/Pm), 3..5: h-path
        bool ipath = g < 3;
        int gc = ipath ? g : g - 3;
        const float* W = (ipath ? Wf : Wt_hh) + gc * 96 + h;
        const float (*src)[Hh] = ipath ? sh.Pm : sh.Xr;
        float a0 = 0.f, a1 = 0.f, a2 = 0.f, a3 = 0.f;
#pragma unroll 8
        for (int k = 0; k < 96; ++k) {
            float w = W[k * 288];
            a0 += src[0][k] * w;
            a1 += src[1][k] * w;
            a2 += src[2][k] * w;
            a3 += src[3][k] * w;
        }
        sh.gd[g][0][h] = a0;
        sh.gd[g][1][h] = a1;
        sh.gd[g][2][h] = a2;
        sh.gd[g][3][h] = a3;
    }
    __syncthreads();

    // C: gate math, 384 threads (r, h)
    if (tid < 384) {
        int h = tid % Hh, rr = tid / Hh;
        float gir = b_ih[h]        + sh.gd[0][rr][h];
        float giz = b_ih[96 + h]   + sh.gd[1][rr][h];
        float gin = b_ih[192 + h]  + sh.gd[2][rr][h];
        float ghr = b_hh[h]        + sh.gd[3][rr][h];
        float ghz = b_hh[96 + h]   + sh.gd[4][rr][h];
        float ghn = b_hh[192 + h]  + sh.gd[5][rr][h];
        float r_  = sigf(gir + ghr);
        float z   = sigf(giz + ghz);
        float nn2 = tanhfast(gin + r_ * ghn);
        float xo  = (1.0f - z) * nn2 + z * sh.Xr[rr][h];
        xout[(i0 + rr) * XS + h] = xo;
        sh.Xo[rr][h] = xo;
    }
    __syncthreads();

    // D: attention projections, 768 threads (w, q, h), 24-k partials
    {
        int h = tid % Hh;
        int q = (tid / Hh) & 3;
        int w = tid / 384;             // 0 = i-proj, 1 = j-proj
        const float* Wp = (w ? Wt_a1j : Wt_a1i) + h;
        float a0 = 0.f, a1 = 0.f, a2 = 0.f, a3 = 0.f;
        int k0 = q * 24;
#pragma unroll 4
        for (int k = k0; k < k0 + 24; ++k) {
            float wv = Wp[k * 96];
            a0 += sh.Xo[0][k] * wv;
            a1 += sh.Xo[1][k] * wv;
            a2 += sh.Xo[2][k] * wv;
            a3 += sh.Xo[3][k] * wv;
        }
        sh.redp[w][q][0][h] = a0;
        sh.redp[w][q][1][h] = a1;
        sh.redp[w][q][2][h] = a2;
        sh.redp[w][q][3][h] = a3;
    }
    __syncthreads();

    // E: finalize projections, 768 threads (w, r, h)
    {
        int h = tid % Hh;
        int rr = (tid / Hh) & 3;
        int w = tid / 384;
        int n = i0 + rr;
        float s = sh.redp[w][0][rr][h] + sh.redp[w][1][rr][h]
                + sh.redp[w][2][rr][h] + sh.redp[w][3][rr][h];
        if (w == 0) Ei[n * Hh + h]  = __expf(-(s + ba1[h]));
        else        EjT[h * Nn + n] = __expf(-s);
    }
}

// ---------------- K2: attn unroll 0 ----------------------------------------
// 4 rows x full j per block. Ei rows + Wa2 staged in LDS (broadcast reads).
__global__ __launch_bounds__(1024) void attn_kernel_u0(
    const float* __restrict__ Ei, const float* __restrict__ EjT,
    const float* __restrict__ Wa2, const float* __restrict__ ba2,
    const int* __restrict__ adj, const float* __restrict__ xB,
    float* __restrict__ xOut)
{
    __shared__ float sm[7168];
    __shared__ float eis[4 * Hh];
    __shared__ float wa2s[Hh];
    int tid = threadIdx.x;
    int i0 = blockIdx.x * 4;
    if (tid < 4 * Hh) eis[tid] = Ei[i0 * Hh + tid];
    if (tid >= 512 && tid < 512 + Hh) wa2s[tid - 512] = Wa2[tid - 512];
    {
        int j = tid;
        int m0 = adj[(i0 + 0) * Nn + j];
        int m1 = adj[(i0 + 1) * Nn + j];
        int m2 = adj[(i0 + 2) * Nn + j];
        int m3 = adj[(i0 + 3) * Nn + j];
        __syncthreads();
        float s0 = 0.f, s1 = 0.f, s2 = 0.f, s3 = 0.f;
#pragma unroll 8
        for (int k = 0; k < Hh; ++k) {
            float e = EjT[k * Nn + j];
            float wk = wa2s[k];                // LDS broadcast
            s0 += __builtin_amdgcn_rcpf(fmaf(eis[k], e, 1.0f)) * wk;
            s1 += __builtin_amdgcn_rcpf(fmaf(eis[96 + k], e, 1.0f)) * wk;
            s2 += __builtin_amdgcn_rcpf(fmaf(eis[192 + k], e, 1.0f)) * wk;
            s3 += __builtin_amdgcn_rcpf(fmaf(eis[288 + k], e, 1.0f)) * wk;
        }
        float b2 = ba2[0];
        sm[0 * Nn + j] = (m0 == 1) ? sigf(s0 + b2) : 0.0f;
        sm[1 * Nn + j] = (m1 == 1) ? sigf(s1 + b2) : 0.0f;
        sm[2 * Nn + j] = (m2 == 1) ? sigf(s2 + b2) : 0.0f;
        sm[3 * Nn + j] = (m3 == 1) ? sigf(s3 + b2) : 0.0f;
    }
    __syncthreads();
    {
        int q = tid >> 7;
        int h = tid & 127;
        if (h < Hh) {
            int jb = q * 128;
            const float* xc = xB + jb * XS + h;
            const float* c0 = sm + 0 * Nn + jb;
            const float* c1 = sm + 1 * Nn + jb;
            const float* c2 = sm + 2 * Nn + jb;
            const float* c3 = sm + 3 * Nn + jb;
            float a0 = 0.f, a1 = 0.f, a2 = 0.f, a3 = 0.f;
#pragma unroll 4
            for (int j = 0; j < 128; ++j) {
                float xv = xc[j * XS];
                a0 += c0[j] * xv;
                a1 += c1[j] * xv;
                a2 += c2[j] * xv;
                a3 += c3[j] * xv;
            }
            sm[4096 + ((q * 4 + 0) * Hh) + h] = a0;
            sm[4096 + ((q * 4 + 1) * Hh) + h] = a1;
            sm[4096 + ((q * 4 + 2) * Hh) + h] = a2;
            sm[4096 + ((q * 4 + 3) * Hh) + h] = a3;
        }
    }
    __syncthreads();
    if (tid < 4 * Hh) {
        int r = tid / Hh, h = tid - r * Hh;
        float v = 0.f;
#pragma unroll
        for (int q = 0; q < 8; ++q)
            v += sm[4096 + ((q * 4 + r) * Hh) + h];
        xOut[(i0 + r) * XS + h] = v;
    }
}

// ---------------- K4: attn unroll 1 + fused output head --------------------
__global__ __launch_bounds__(1024) void attn_kernel_u1(
    const float* __restrict__ Ei, const float* __restrict__ EjT,
    const float* __restrict__ Wa2, const float* __restrict__ ba2,
    const int* __restrict__ adj, const float* __restrict__ xB,
    const float* __restrict__ Wt_o1, const float* __restrict__ bo1,
    const float* __restrict__ Wt_o2, const float* __restrict__ bo2,
    const float* __restrict__ Wp1, const float* __restrict__ bp1,
    const float* __restrict__ Wp2, const float* __restrict__ bp2,
    float* __restrict__ out)
{
    __shared__ float sm[7168];
    __shared__ float eis[4 * Hh];
    __shared__ float wa2s[Hh];
    __shared__ float hd[3][4][Hh];    // xout, t1, t2 for the fused head
    int tid = threadIdx.x;
    int i0 = blockIdx.x * 4;
    if (tid < 4 * Hh) eis[tid] = Ei[i0 * Hh + tid];
    if (tid >= 512 && tid < 512 + Hh) wa2s[tid - 512] = Wa2[tid - 512];
    {
        int j = tid;
        int m0 = adj[(i0 + 0) * Nn + j];
        int m1 = adj[(i0 + 1) * Nn + j];
        int m2 = adj[(i0 + 2) * Nn + j];
        int m3 = adj[(i0 + 3) * Nn + j];
        __syncthreads();
        float s0 = 0.f, s1 = 0.f, s2 = 0.f, s3 = 0.f;
#pragma unroll 8
        for (int k = 0; k < Hh; ++k) {
            float e = EjT[k * Nn + j];
            float wk = wa2s[k];                // LDS broadcast
            s0 += __builtin_amdgcn_rcpf(fmaf(eis[k], e, 1.0f)) * wk;
            s1 += __builtin_amdgcn_rcpf(fmaf(eis[96 + k], e, 1.0f)) * wk;
            s2 += __builtin_amdgcn_rcpf(fmaf(eis[192 + k], e, 1.0f)) * wk;
            s3 += __builtin_amdgcn_rcpf(fmaf(eis[288 + k], e, 1.0f)) * wk;
        }
        float b2 = ba2[0];
        sm[0 * Nn + j] = (m0 == 1) ? sigf(s0 + b2) : 0.0f;
        sm[1 * Nn + j] = (m1 == 1) ? sigf(s1 + b2) : 0.0f;
        sm[2 * Nn + j] = (m2 == 1) ? sigf(s2 + b2) : 0.0f;
        sm[3 * Nn + j] = (m3 == 1) ? sigf(s3 + b2) : 0.0f;
    }
    __syncthreads();
    {
        int q = tid >> 7;
        int h = tid & 127;
        if (h < Hh) {
            int jb = q * 128;
            const float* xc = xB + jb * XS + h;
            const float* c0 = sm + 0 * Nn + jb;
            const float* c1 = sm + 1 * Nn + jb;
            const float* c2 = sm + 2 * Nn + jb;
            const float* c3 = sm + 3 * Nn + jb;
            float a0 = 0.f, a1 = 0.f, a2 = 0.f, a3 = 0.f;
#pragma unroll 4
            for (int j = 0; j < 128; ++j) {
                float xv = xc[j * XS];
                a0 += c0[j] * xv;
                a1 += c1[j] * xv;
                a2 += c2[j] * xv;
                a3 += c3[j] * xv;
            }
            sm[4096 + ((q * 4 + 0) * Hh) + h] = a0;
            sm[4096 + ((q * 4 + 1) * Hh) + h] = a1;
            sm[4096 + ((q * 4 + 2) * Hh) + h] = a2;
            sm[4096 + ((q * 4 + 3) * Hh) + h] = a3;
        }
    }
    __syncthreads();
    if (tid < 4 * Hh) {
        int r = tid / Hh, h = tid - r * Hh;
        float v = 0.f;
#pragma unroll
        for (int q = 0; q < 8; ++q)
            v += sm[4096 + ((q * 4 + r) * Hh) + h];
        hd[0][r][h] = v;
    }
    __syncthreads();
    if (tid < 4 * Hh) {
        int r = tid / Hh, h = tid - r * Hh;
        const float* w = Wt_o1 + h;
        const float* xr = hd[0][r];
        float acc = bo1[h];
        for (int k = 0; k < Hh; ++k) acc += xr[k] * w[k * 96];
        hd[1][r][h] = leakyf(acc);
    }
    __syncthreads();
    if (tid < 4 * Hh) {
        int r = tid / Hh, h = tid - r * Hh;
        const float* w = Wt_o2 + h;
        const float* xr = hd[1][r];
        float acc = bo2[h];
        for (int k = 0; k < Hh; ++k) acc += xr[k] * w[k * 96];
        hd[2][r][h] = leakyf(acc);
    }
    __syncthreads();
    if (tid < 8) {
        int r = tid >> 1, which = tid & 1;
        const float* wp = which ? Wp2 : Wp1;
        const float* xr = hd[2][r];
        float acc = 0.f;
        for (int k = 0; k < Hh; ++k) acc += xr[k] * wp[k];
        float b = which ? bp2[0] : bp1[0];
        out[which * Nn + i0 + r] = sigf(acc + b);
    }
}

extern "C" void kernel_launch(void* const* d_in, const int* in_sizes, int n_in,
                              void* d_out, int out_size, void* d_ws, size_t ws_size,
                              hipStream_t stream)
{
    const float* x_in   = (const float*)d_in[0];
    const int*   ei     = (const int*)d_in[1];
    const int*   adj    = (const int*)d_in[2];
    const float* W_init = (const float*)d_in[3];
    const float* b_init = (const float*)d_in[4];
    const float* W_ggc  = (const float*)d_in[5];
    const float* W_ih   = (const float*)d_in[6];
    const float* W_hh   = (const float*)d_in[7];
    const float* b_ih   = (const float*)d_in[8];
    const float* b_hh   = (const float*)d_in[9];
    const float* Wa1    = (const float*)d_in[10];
    const float* ba1    = (const float*)d_in[11];
    const float* Wa2    = (const float*)d_in[12];
    const float* ba2    = (const float*)d_in[13];
    const float* Wo1    = (const float*)d_in[14];
    const float* bo1    = (const float*)d_in[15];
    const float* Wo2    = (const float*)d_in[16];
    const float* bo2    = (const float*)d_in[17];
    const float* Wp1    = (const float*)d_in[18];
    const float* bp1    = (const float*)d_in[19];
    const float* Wp2    = (const float*)d_in[20];
    const float* bp2    = (const float*)d_in[21];
    float* out = (float*)d_out;

    // workspace layout, ~2.7 MB (no deg/bucket arrays anymore)
    float* ws     = (float*)d_ws;
    float* xA     = ws;                     // (N, XS)
    float* xB     = xA + Nn * XS;           // (N, XS)
    float* xC     = xB + Nn * XS;           // (N, XS)
    float* Ei     = xC + Nn * XS;           // (N, 96)
    float* EjT    = Ei + NH;                // (96, N)
    float* Wt_hh  = EjT + NH;               // 96*288
    float* Wf     = Wt_hh + 27648;          // 96*288
    float* Wt_a1i = Wf + 27648;             // 96*96
    float* Wt_a1j = Wt_a1i + 9216;
    float* Wt_o1  = Wt_a1j + 9216;
    float* Wt_o2  = Wt_o1 + 9216;

    setup_kernel<<<96, 1024, 0, stream>>>(
        W_hh, Wa1, Wo1, Wo2, W_ggc, W_ih, x_in, W_init, b_init,
        Wt_hh, Wt_a1i, Wt_a1j, Wt_o1, Wt_o2, Wf, xA);

    // unroll 0: xA -> xB -> xC
    gru_kernel<<<256, 768, 0, stream>>>(
        xA, ei, Wf, Wt_hh, b_ih, b_hh, Wt_a1i, Wt_a1j, ba1,
        xB, Ei, EjT);
    attn_kernel_u0<<<256, 1024, 0, stream>>>(
        Ei, EjT, Wa2, ba2, adj, xB, xC);

    // unroll 1: xC -> xB -> (head fused) -> out
    gru_kernel<<<256, 768, 0, stream>>>(
        xC, ei, Wf, Wt_hh, b_ih, b_hh, Wt_a1i, Wt_a1j, ba1,
        xB, Ei, EjT);
    attn_kernel_u1<<<256, 1024, 0, stream>>>(
        Ei, EjT, Wa2, ba2, adj, xB,
        Wt_o1, bo1, Wt_o2, bo2, Wp1, bp1, Wp2, bp2, out);
}